// Round 2
// baseline (983.217 us; speedup 1.0000x reference)
//
#include <hip/hip_runtime.h>

// GCN: 2x GCNConv(sym-norm, self-loops) + mean-pool + 2 MLP heads.
// R4: edge-parallel tile-phased aggregation with LDS accumulators.
//  - binB: tile-only (8-bin) sort per dst-bucket (register counters + one
//    4096-elem scan); emits edata (src|ld<<18, ew), tileOff[512][9], dinv.
//  - node1 pre-scales: h' = (X@W1)*dinv  ->  agg = dinv*(sum h'[src]*ew + h'),
//    removing the per-edge dinv[src] gather.
//  - agg kernels: block = 1 bucket (512 nodes), acc[512][17] f32 in LDS,
//    4 lanes/edge, atomicAdd (ds_add_f32); tiles swept in lockstep (512
//    blocks x 1024 thr = 2 blocks/CU co-resident) for L2 locality.
//  - node2 (b1+leaky+@W2, pre-scale by dinv) fused into aggA epilogue.

#define NBUCK 512          // coarse buckets = dst >> 9
#define BCAP  10240        // slack capacity per bucket (mean 8192, sigma ~90)
#define CHUNK 4096         // edges per pass-A block
#define NTILE 8            // src tiles = src >> 15 (2MB of h' per tile)
#define TSH   15

__device__ __forceinline__ float leaky(float x) { return x > 0.f ? x : 0.01f * x; }

// --- Pass A: bin edges by dst>>9 into slack-capacity coarse buckets ------
__global__ __launch_bounds__(256) void
binA_kernel(const int* __restrict__ src, const int* __restrict__ dst,
            const float* __restrict__ ew, int* __restrict__ bucketCursor,
            int2* __restrict__ coarse, int E) {
    __shared__ int lhist[NBUCK], lbase[NBUCK], lcur[NBUCK], gbase[NBUCK];
    __shared__ int tmp[256];
    __shared__ int2 stag[CHUNK];
    __shared__ unsigned short sbuck[CHUNK];
    int t = threadIdx.x;
    int base = blockIdx.x * CHUNK;
    for (int b = t; b < NBUCK; b += 256) { lhist[b] = 0; lcur[b] = 0; }
    __syncthreads();
    int n = min(CHUNK, E - base);
    int myDst[16], mySrc[16]; float myEw[16];
#pragma unroll
    for (int k = 0; k < 16; ++k) {
        int j = t + k * 256;                       // coalesced
        if (j < n) {
            int d = dst[base + j];
            myDst[k] = d; mySrc[k] = src[base + j]; myEw[k] = ew[base + j];
            atomicAdd(&lhist[d >> 9], 1);
        } else myDst[k] = -1;
    }
    __syncthreads();
    // exclusive scan of lhist (512 entries, 256 threads, pair trick)
    tmp[t] = lhist[2 * t] + lhist[2 * t + 1];
    __syncthreads();
    for (int off = 1; off < 256; off <<= 1) {
        int v = (t >= off) ? tmp[t - off] : 0;
        __syncthreads();
        tmp[t] += v;
        __syncthreads();
    }
    int pb = (t == 0) ? 0 : tmp[t - 1];
    lbase[2 * t] = pb;
    lbase[2 * t + 1] = pb + lhist[2 * t];
    __syncthreads();
    // reserve global space per bucket (one atomic per non-empty bucket)
    for (int b = t; b < NBUCK; b += 256) {
        int c = lhist[b];
        gbase[b] = c ? atomicAdd(&bucketCursor[b], c) : 0;
    }
    // stage into LDS, sorted by bucket; pack (src | ldst<<18, ew)
    for (int k = 0; k < 16; ++k) {
        int d = myDst[k];
        if (d >= 0) {
            int b = d >> 9;
            int p = lbase[b] + atomicAdd(&lcur[b], 1);
            stag[p] = make_int2(mySrc[k] | ((d & 511) << 18), __float_as_int(myEw[k]));
            sbuck[p] = (unsigned short)b;
        }
    }
    __syncthreads();
    // write out: consecutive j -> consecutive addresses within bucket runs
    for (int j = t; j < n; j += 256) {
        int b = sbuck[j];
        coarse[(size_t)b * BCAP + gbase[b] + (j - lbase[b])] = stag[j];
    }
}

// --- scan bucket counts -> bucket bases (1 block x 512) ------------------
__global__ void bscan_kernel(const int* __restrict__ bucketCursor,
                             int* __restrict__ bucketBase) {
    __shared__ int s[NBUCK];
    int t = threadIdx.x;
    int v = bucketCursor[t];
    s[t] = v;
    __syncthreads();
    for (int off = 1; off < NBUCK; off <<= 1) {
        int x = (t >= off) ? s[t - off] : 0;
        __syncthreads();
        s[t] += x;
        __syncthreads();
    }
    bucketBase[t] = s[t] - v;
}

// --- Pass B: tile-only (8-bin) sort within each bucket -------------------
// Register tile-counters per thread + one 4096-elem LDS scan; stable
// placement not required (agg accumulates with atomics). Emits edata,
// per-bucket tileOff[9], and dinv.
__global__ __launch_bounds__(512) void
binB_kernel(const int* __restrict__ bucketCursor, const int* __restrict__ bucketBase,
            const int2* __restrict__ coarse, int2* __restrict__ edata,
            float* __restrict__ dinv, int* __restrict__ tileOff) {
    __shared__ int scanM[NTILE * 512];   // [tile][thread] counts -> excl. offsets
    __shared__ float ldeg[512];
    __shared__ int tmp[512];
    int b = blockIdx.x, t = threadIdx.x;
    ldeg[t] = 0.f;
    __syncthreads();
    int cnt = bucketCursor[b];
    int gb  = bucketBase[b];
    const int2* cb = coarse + (size_t)b * BCAP;
    int c0 = 0, c1 = 0, c2 = 0, c3 = 0, c4 = 0, c5 = 0, c6 = 0, c7 = 0;
    for (int j = t; j < cnt; j += 512) {
        int2 e = cb[j];
        int tt = (e.x & 0x3FFFF) >> TSH;
        atomicAdd(&ldeg[(e.x >> 18) & 511], __int_as_float(e.y));
        c0 += (tt == 0); c1 += (tt == 1); c2 += (tt == 2); c3 += (tt == 3);
        c4 += (tt == 4); c5 += (tt == 5); c6 += (tt == 6); c7 += (tt == 7);
    }
    scanM[0 * 512 + t] = c0; scanM[1 * 512 + t] = c1;
    scanM[2 * 512 + t] = c2; scanM[3 * 512 + t] = c3;
    scanM[4 * 512 + t] = c4; scanM[5 * 512 + t] = c5;
    scanM[6 * 512 + t] = c6; scanM[7 * 512 + t] = c7;
    __syncthreads();
    // exclusive scan over 4096 (tile-major): thread owns [8t, 8t+8)
    int base8 = t * 8, s = 0;
#pragma unroll
    for (int k = 0; k < 8; ++k) s += scanM[base8 + k];
    tmp[t] = s;
    __syncthreads();
    for (int off = 1; off < 512; off <<= 1) {
        int v = (t >= off) ? tmp[t - off] : 0;
        __syncthreads();
        tmp[t] += v;
        __syncthreads();
    }
    int run = tmp[t] - s;
#pragma unroll
    for (int k = 0; k < 8; ++k) { int v = scanM[base8 + k]; scanM[base8 + k] = run; run += v; }
    __syncthreads();
    int tOff = (t < 8) ? scanM[t * 512] : cnt;   // capture before cursors clobber
    __syncthreads();
    // pass 2: place edges; scanM slot (tile, t) is this thread's private cursor
    for (int j = t; j < cnt; j += 512) {
        int2 e = cb[j];
        int tt = (e.x & 0x3FFFF) >> TSH;
        int idx = tt * 512 + t;
        int p = scanM[idx]; scanM[idx] = p + 1;
        edata[gb + p] = e;
    }
    if (t < 9) tileOff[b * 9 + t] = gb + tOff;
    int node = b * 512 + t;
    dinv[node] = rsqrtf(1.0f + ldeg[t]);         // +1 = self-loop weight
}

// --- node pass 1: h' = (X@W1) * dinv -------------------------------------
__global__ void node1_kernel(const float* __restrict__ X, const float* __restrict__ W1,
                             const float* __restrict__ dinv, float* __restrict__ h, int N) {
    __shared__ float w[48];
    if (threadIdx.x < 48) w[threadIdx.x] = W1[threadIdx.x];
    __syncthreads();
    int i = blockIdx.x * blockDim.x + threadIdx.x;
    if (i >= N) return;
    float x0 = X[3 * i], x1 = X[3 * i + 1], x2 = X[3 * i + 2];
    float di = dinv[i];
    float4* hp = (float4*)(h + (size_t)i * 16);
#pragma unroll
    for (int k = 0; k < 4; ++k) {
        float4 v;
        v.x = (x0 * w[4 * k + 0] + x1 * w[16 + 4 * k + 0] + x2 * w[32 + 4 * k + 0]) * di;
        v.y = (x0 * w[4 * k + 1] + x1 * w[16 + 4 * k + 1] + x2 * w[32 + 4 * k + 1]) * di;
        v.z = (x0 * w[4 * k + 2] + x1 * w[16 + 4 * k + 2] + x2 * w[32 + 4 * k + 2]) * di;
        v.w = (x0 * w[4 * k + 3] + x1 * w[16 + 4 * k + 3] + x2 * w[32 + 4 * k + 3]) * di;
        hp[k] = v;
    }
}

// --- agg pass 1: edge-parallel LDS-accumulate, fused node2 ---------------
// block = 1 dst-bucket (512 nodes); 1024 thr = 256 edge-groups x 4 lanes.
// acc stride 17 floats to spread LDS banks for ds_add.
__global__ __launch_bounds__(1024, 8) void
aggA_kernel(const int* __restrict__ tileOff, const int2* __restrict__ edata,
            const float* __restrict__ dinv, const float* __restrict__ hprime,
            const float* __restrict__ b1, const float* __restrict__ W2,
            float* __restrict__ h2) {
    __shared__ float acc[512 * 17];
    __shared__ float w[256];
    __shared__ float bb[16];
    __shared__ int toff[9];
    int b = blockIdx.x, t = threadIdx.x;
    if (t < 256) w[t] = W2[t];
    else if (t < 272) bb[t - 256] = b1[t - 256];
    else if (t >= 512 && t < 521) toff[t - 512] = tileOff[b * 9 + t - 512];
    for (int i = t; i < 512 * 17; i += 1024) acc[i] = 0.f;
    __syncthreads();
    int g = t >> 2, l = t & 3;
    const float4* hp = (const float4*)hprime;
    for (int tt = 0; tt < NTILE; ++tt) {
        int e1 = toff[tt + 1];
        for (int j = toff[tt] + g; j < e1; j += 256) {
            int2 ed = edata[j];
            int s = ed.x & 0x3FFFF;
            float ewv = __int_as_float(ed.y);
            float4 v = hp[(size_t)s * 4 + l];
            float* a = acc + ((ed.x >> 18) & 511) * 17 + 4 * l;
            atomicAdd(a + 0, v.x * ewv);
            atomicAdd(a + 1, v.y * ewv);
            atomicAdd(a + 2, v.z * ewv);
            atomicAdd(a + 3, v.w * ewv);
        }
        __syncthreads();
    }
    // epilogue: x = leaky(dinv*(acc + h'_self) + b1); h2' = (x@W2)*dinv
    int i = t & 511, hf = t >> 9;
    int node = b * 512 + i;
    float di = dinv[node];
    const float4* hpn = hp + (size_t)node * 4;
    float x[16];
#pragma unroll
    for (int qq = 0; qq < 4; ++qq) {
        float4 hv = hpn[qq];
        x[4 * qq + 0] = leaky(di * (acc[i * 17 + 4 * qq + 0] + hv.x) + bb[4 * qq + 0]);
        x[4 * qq + 1] = leaky(di * (acc[i * 17 + 4 * qq + 1] + hv.y) + bb[4 * qq + 1]);
        x[4 * qq + 2] = leaky(di * (acc[i * 17 + 4 * qq + 2] + hv.z) + bb[4 * qq + 2]);
        x[4 * qq + 3] = leaky(di * (acc[i * 17 + 4 * qq + 3] + hv.w) + bb[4 * qq + 3]);
    }
    float4 o0, o1;
#pragma unroll
    for (int ff = 0; ff < 4; ++ff) {
        float a = 0.f;
#pragma unroll
        for (int q = 0; q < 16; ++q) a += x[q] * w[q * 16 + hf * 8 + ff];
        ((float*)&o0)[ff] = a * di;
    }
#pragma unroll
    for (int ff = 0; ff < 4; ++ff) {
        float a = 0.f;
#pragma unroll
        for (int q = 0; q < 16; ++q) a += x[q] * w[q * 16 + hf * 8 + 4 + ff];
        ((float*)&o1)[ff] = a * di;
    }
    float4* op = (float4*)h2 + (size_t)node * 4 + hf * 2;
    op[0] = o0; op[1] = o1;
}

// --- agg pass 2: same structure; epilogue = dinv*(acc + self) ------------
__global__ __launch_bounds__(1024, 8) void
aggB_kernel(const int* __restrict__ tileOff, const int2* __restrict__ edata,
            const float* __restrict__ dinv, const float* __restrict__ h2prime,
            float* __restrict__ agg2) {
    __shared__ float acc[512 * 17];
    __shared__ int toff[9];
    int b = blockIdx.x, t = threadIdx.x;
    if (t >= 512 && t < 521) toff[t - 512] = tileOff[b * 9 + t - 512];
    for (int i = t; i < 512 * 17; i += 1024) acc[i] = 0.f;
    __syncthreads();
    int g = t >> 2, l = t & 3;
    const float4* hp = (const float4*)h2prime;
    for (int tt = 0; tt < NTILE; ++tt) {
        int e1 = toff[tt + 1];
        for (int j = toff[tt] + g; j < e1; j += 256) {
            int2 ed = edata[j];
            int s = ed.x & 0x3FFFF;
            float ewv = __int_as_float(ed.y);
            float4 v = hp[(size_t)s * 4 + l];
            float* a = acc + ((ed.x >> 18) & 511) * 17 + 4 * l;
            atomicAdd(a + 0, v.x * ewv);
            atomicAdd(a + 1, v.y * ewv);
            atomicAdd(a + 2, v.z * ewv);
            atomicAdd(a + 3, v.w * ewv);
        }
        __syncthreads();
    }
    int i = t & 511, hf = t >> 9;
    int node = b * 512 + i;
    float di = dinv[node];
    const float4* sp = hp + (size_t)node * 4 + hf * 2;
    float4 s0 = sp[0], s1 = sp[1];
    int a0 = i * 17 + hf * 8;
    float4 o0, o1;
    o0.x = di * (acc[a0 + 0] + s0.x); o0.y = di * (acc[a0 + 1] + s0.y);
    o0.z = di * (acc[a0 + 2] + s0.z); o0.w = di * (acc[a0 + 3] + s0.w);
    o1.x = di * (acc[a0 + 4] + s1.x); o1.y = di * (acc[a0 + 5] + s1.y);
    o1.z = di * (acc[a0 + 6] + s1.z); o1.w = di * (acc[a0 + 7] + s1.w);
    float4* op = (float4*)agg2 + (size_t)node * 4 + hf * 2;
    op[0] = o0; op[1] = o1;
}

// --- tiny MLP head: 16 ->16 ->16 ->2 -------------------------------------
__device__ void head_mlp(const float* pooled,
                         const float* __restrict__ Wa, const float* __restrict__ ba,
                         const float* __restrict__ Wb, const float* __restrict__ bb,
                         const float* __restrict__ Wc, const float* __restrict__ bc,
                         float* o) {
    float t[16], u[16];
#pragma unroll
    for (int f = 0; f < 16; ++f) {
        float a = ba[f];
        for (int k = 0; k < 16; ++k) a += pooled[k] * Wa[k * 16 + f];
        t[f] = leaky(a);
    }
#pragma unroll
    for (int f = 0; f < 16; ++f) {
        float a = bb[f];
        for (int k = 0; k < 16; ++k) a += t[k] * Wb[k * 16 + f];
        u[f] = leaky(a);
    }
    float o0 = bc[0], o1 = bc[1];
    for (int k = 0; k < 16; ++k) { o0 += u[k] * Wc[2 * k]; o1 += u[k] * Wc[2 * k + 1]; }
    o[0] = o0; o[1] = o1;
}

// --- pool (block per graph; Batching sorted -> binary search) + heads ----
__global__ void pool_head_kernel(const float* __restrict__ agg2, const float* __restrict__ b2,
                                 const int* __restrict__ batching, int N,
                                 const float* __restrict__ Wp1, const float* __restrict__ bp1,
                                 const float* __restrict__ Wp2, const float* __restrict__ bp2,
                                 const float* __restrict__ Wp3, const float* __restrict__ bp3,
                                 const float* __restrict__ Wt1, const float* __restrict__ bt1,
                                 const float* __restrict__ Wt2, const float* __restrict__ bt2,
                                 const float* __restrict__ Wt3, const float* __restrict__ bt3,
                                 float* __restrict__ out) {
    int g = blockIdx.x;
    __shared__ int bounds[2];
    if (threadIdx.x < 2) {
        int v = g + (int)threadIdx.x;
        int lo = 0, hi = N;
        while (lo < hi) { int m = (lo + hi) >> 1; if (batching[m] < v) lo = m + 1; else hi = m; }
        bounds[threadIdx.x] = lo;
    }
    __syncthreads();
    int lo = bounds[0], hi = bounds[1];
    int f = threadIdx.x & 15, r = threadIdx.x >> 4;    // 16 rows x 16 features
    float bf = b2[f];
    float acc = 0.f;
    for (int i = lo + r; i < hi; i += 16) acc += leaky(agg2[(size_t)i * 16 + f] + bf);
    __shared__ float red[16][17];
    red[r][f] = acc;
    __syncthreads();
    __shared__ float pooled[16];
    if (r == 0) {
        float s = 0.f;
#pragma unroll
        for (int k = 0; k < 16; ++k) s += red[k][f];
        pooled[f] = s / fmaxf((float)(hi - lo), 1.0f);
    }
    __syncthreads();
    if (threadIdx.x == 0) {
        float o[2];
        head_mlp(pooled, Wp1, bp1, Wp2, bp2, Wp3, bp3, o);
        out[4 * g + 0] = o[0]; out[4 * g + 1] = o[1];
    } else if (threadIdx.x == 1) {
        float o[2];
        head_mlp(pooled, Wt1, bt1, Wt2, bt2, Wt3, bt3, o);
        out[4 * g + 2] = o[0]; out[4 * g + 3] = o[1];
    }
}

extern "C" void kernel_launch(void* const* d_in, const int* in_sizes, int n_in,
                              void* d_out, int out_size, void* d_ws, size_t ws_size,
                              hipStream_t stream) {
    const float* X        = (const float*)d_in[0];
    const int*   ei       = (const int*)d_in[1];
    const float* ew       = (const float*)d_in[2];
    const int*   batching = (const int*)d_in[3];
    const float* W1  = (const float*)d_in[5];  const float* b1  = (const float*)d_in[6];
    const float* W2  = (const float*)d_in[7];  const float* b2  = (const float*)d_in[8];
    const float* Wp1 = (const float*)d_in[9];  const float* bp1 = (const float*)d_in[10];
    const float* Wp2 = (const float*)d_in[11]; const float* bp2 = (const float*)d_in[12];
    const float* Wp3 = (const float*)d_in[13]; const float* bp3 = (const float*)d_in[14];
    const float* Wt1 = (const float*)d_in[15]; const float* bt1 = (const float*)d_in[16];
    const float* Wt2 = (const float*)d_in[17]; const float* bt2 = (const float*)d_in[18];
    const float* Wt3 = (const float*)d_in[19]; const float* bt3 = (const float*)d_in[20];

    const int N = in_sizes[3];        // 262144 = 512 * 512
    const int E = in_sizes[2];        // 4194304
    const int G = out_size / 4;       // 1024
    const int* src = ei;
    const int* dst = ei + E;

    char* ws = (char*)d_ws;
    size_t off = 0;
    int2*  edata = (int2*)(ws + off);  off += (size_t)E * 8;              // 32 MB fine CSR
    char*  regionA = ws + off;         off += (size_t)N * 64 * 3;         // 48 MB
    // regionA phase 1: coarse buckets (40 MB); phase 2: h' | h2' | agg2
    int2*  coarse = (int2*)regionA;
    float* hprime = (float*)regionA;
    float* h2     = (float*)(regionA + (size_t)N * 64);
    float* agg2   = (float*)(regionA + (size_t)N * 128);
    int*   bucketCursor = (int*)(ws + off); off += NBUCK * 4;
    int*   bucketBase   = (int*)(ws + off); off += NBUCK * 4;
    float* dinv  = (float*)(ws + off); off += (size_t)N * 4;
    int*   tileOff = (int*)(ws + off); off += (size_t)NBUCK * 9 * 4;
    float* out   = (float*)d_out;

    hipMemsetAsync(bucketCursor, 0, NBUCK * 4, stream);

    const int tb = 256;
    binA_kernel<<<(E + CHUNK - 1) / CHUNK, tb, 0, stream>>>(src, dst, ew, bucketCursor, coarse, E);
    bscan_kernel<<<1, NBUCK, 0, stream>>>(bucketCursor, bucketBase);
    binB_kernel<<<NBUCK, 512, 0, stream>>>(bucketCursor, bucketBase, coarse, edata, dinv, tileOff);
    node1_kernel<<<(N + tb - 1) / tb, tb, 0, stream>>>(X, W1, dinv, hprime, N);
    aggA_kernel<<<NBUCK, 1024, 0, stream>>>(tileOff, edata, dinv, hprime, b1, W2, h2);
    aggB_kernel<<<NBUCK, 1024, 0, stream>>>(tileOff, edata, dinv, h2, agg2);
    pool_head_kernel<<<G, tb, 0, stream>>>(agg2, b2, batching, N,
                                           Wp1, bp1, Wp2, bp2, Wp3, bp3,
                                           Wt1, bt1, Wt2, bt2, Wt3, bt3, out);
}

// Round 3
// 429.605 us; speedup vs baseline: 2.2887x; 2.2887x over previous
//
#include <hip/hip_runtime.h>

// GCN: 2x GCNConv(sym-norm, self-loops) + mean-pool + 2 MLP heads.
// R5: gather-based tile-phased aggregation (proven R3 structure) + no
// float LDS atomics anywhere (R4 lesson: float LDS atomicAdd is a CAS
// retry loop on gfx950, ~20us per million ops under contention).
//  - binB: (ld,tile) counting sort with INT atomics only; deg computed by
//    per-node gather-sum over the just-written (L2-hot) edata run.
//  - node1 pre-scales: h' = (X@W1)*dinv -> per-edge work is acc += h'[s]*ew
//    (no dinv[src] gather); epilogues multiply by dinv[i] once.
//  - agg kernels: 4 lanes/node, 2 nodes/group, 8 src-tiles swept in
//    lockstep (1024 blocks x 512 thr co-resident) for L2 locality.
//  - node2 (b1+leaky+@W2, then *dinv) fused into aggA epilogue.

#define NBUCK 512          // coarse buckets = dst >> 9
#define BCAP  10240        // slack capacity per bucket (mean 8192, sigma ~90)
#define CHUNK 4096         // edges per pass-A block
#define NTILE 8            // src tiles = src >> 15 (2MB of h' per tile)
#define TSH   15

__device__ __forceinline__ float leaky(float x) { return x > 0.f ? x : 0.01f * x; }

// --- Pass A: bin edges by dst>>9 into slack-capacity coarse buckets ------
__global__ __launch_bounds__(256) void
binA_kernel(const int* __restrict__ src, const int* __restrict__ dst,
            const float* __restrict__ ew, int* __restrict__ bucketCursor,
            int2* __restrict__ coarse, int E) {
    __shared__ int lhist[NBUCK], lbase[NBUCK], lcur[NBUCK], gbase[NBUCK];
    __shared__ int tmp[256];
    __shared__ int2 stag[CHUNK];
    __shared__ unsigned short sbuck[CHUNK];
    int t = threadIdx.x;
    int base = blockIdx.x * CHUNK;
    for (int b = t; b < NBUCK; b += 256) { lhist[b] = 0; lcur[b] = 0; }
    __syncthreads();
    int n = min(CHUNK, E - base);
    int myDst[16], mySrc[16]; float myEw[16];
#pragma unroll
    for (int k = 0; k < 16; ++k) {
        int j = t + k * 256;                       // coalesced
        if (j < n) {
            int d = dst[base + j];
            myDst[k] = d; mySrc[k] = src[base + j]; myEw[k] = ew[base + j];
            atomicAdd(&lhist[d >> 9], 1);
        } else myDst[k] = -1;
    }
    __syncthreads();
    // exclusive scan of lhist (512 entries, 256 threads, pair trick)
    tmp[t] = lhist[2 * t] + lhist[2 * t + 1];
    __syncthreads();
    for (int off = 1; off < 256; off <<= 1) {
        int v = (t >= off) ? tmp[t - off] : 0;
        __syncthreads();
        tmp[t] += v;
        __syncthreads();
    }
    int pb = (t == 0) ? 0 : tmp[t - 1];
    lbase[2 * t] = pb;
    lbase[2 * t + 1] = pb + lhist[2 * t];
    __syncthreads();
    // reserve global space per bucket (one atomic per non-empty bucket)
    for (int b = t; b < NBUCK; b += 256) {
        int c = lhist[b];
        gbase[b] = c ? atomicAdd(&bucketCursor[b], c) : 0;
    }
    // stage into LDS, sorted by bucket; pack (src | ldst<<18, ew)
    for (int k = 0; k < 16; ++k) {
        int d = myDst[k];
        if (d >= 0) {
            int b = d >> 9;
            int p = lbase[b] + atomicAdd(&lcur[b], 1);
            stag[p] = make_int2(mySrc[k] | ((d & 511) << 18), __float_as_int(myEw[k]));
            sbuck[p] = (unsigned short)b;
        }
    }
    __syncthreads();
    // write out: consecutive j -> consecutive addresses within bucket runs
    for (int j = t; j < n; j += 256) {
        int b = sbuck[j];
        coarse[(size_t)b * BCAP + gbase[b] + (j - lbase[b])] = stag[j];
    }
}

// --- scan bucket counts -> bucket bases (1 block x 512) ------------------
__global__ void bscan_kernel(const int* __restrict__ bucketCursor,
                             int* __restrict__ bucketBase, int* __restrict__ row,
                             int N, int E) {
    __shared__ int s[NBUCK];
    int t = threadIdx.x;
    int v = bucketCursor[t];
    s[t] = v;
    __syncthreads();
    for (int off = 1; off < NBUCK; off <<= 1) {
        int x = (t >= off) ? s[t - off] : 0;
        __syncthreads();
        s[t] += x;
        __syncthreads();
    }
    bucketBase[t] = s[t] - v;
    if (t == 0) row[N] = E;
}

// --- Pass B: (ld,tile) counting sort; deg via gather-sum (no f32 atomics)
__global__ __launch_bounds__(512) void
binB_kernel(const int* __restrict__ bucketCursor, const int* __restrict__ bucketBase,
            const int2* __restrict__ coarse, int2* __restrict__ edata,
            int* __restrict__ row, float* __restrict__ dinv,
            uint4* __restrict__ tcnt) {
    __shared__ int loff[NBUCK * NTILE];   // counts -> exclusive offsets
    __shared__ int lcur[NBUCK * NTILE];   // placement cursors
    __shared__ int tmp[512];
    int b = blockIdx.x, t = threadIdx.x;
    for (int i = t; i < NBUCK * NTILE; i += 512) { loff[i] = 0; lcur[i] = 0; }
    __syncthreads();
    int cnt = bucketCursor[b];
    int gb  = bucketBase[b];
    const int2* cb = coarse + (size_t)b * BCAP;
    for (int j = t; j < cnt; j += 512) {
        int e = cb[j].x;
        atomicAdd(&loff[(((e >> 18) & 511) << 3) | ((e & 0x3FFFF) >> TSH)], 1);
    }
    __syncthreads();
    // exclusive scan over 4096 (thread t owns node t's 8 tile-bins)
    int base8 = t * 8, s = 0;
#pragma unroll
    for (int k = 0; k < 8; ++k) s += loff[base8 + k];
    tmp[t] = s;
    __syncthreads();
    for (int off = 1; off < 512; off <<= 1) {
        int v = (t >= off) ? tmp[t - off] : 0;
        __syncthreads();
        tmp[t] += v;
        __syncthreads();
    }
    int run = tmp[t] - s;
#pragma unroll
    for (int k = 0; k < 8; ++k) { int v = loff[base8 + k]; loff[base8 + k] = run; run += v; }
    __syncthreads();
    // per-node row/tcnt (loff stays intact; lcur is the moving cursor)
    int o[9];
#pragma unroll
    for (int k = 0; k < 8; ++k) o[k] = loff[base8 + k];
    o[8] = (t == 511) ? cnt : loff[base8 + 8];
    int node = b * 512 + t;
    row[node] = gb + o[0];
    uint4 p;
    p.x = (unsigned)(o[1] - o[0]) | ((unsigned)(o[2] - o[1]) << 16);
    p.y = (unsigned)(o[3] - o[2]) | ((unsigned)(o[4] - o[3]) << 16);
    p.z = (unsigned)(o[5] - o[4]) | ((unsigned)(o[6] - o[5]) << 16);
    p.w = (unsigned)(o[7] - o[6]) | ((unsigned)(o[8] - o[7]) << 16);
    tcnt[node] = p;
    // placement
    for (int j = t; j < cnt; j += 512) {
        int2 e = cb[j];
        int sv = e.x & 0x3FFFF;
        int key = (((e.x >> 18) & 511) << 3) | (sv >> TSH);
        int pos = gb + loff[key] + atomicAdd(&lcur[key], 1);
        edata[pos] = make_int2(sv, e.y);
    }
    __syncthreads();
    // deg = sum of ew over this node's contiguous (L2-hot) edata run
    float dsum = 0.f;
    for (int j = gb + o[0], e1 = gb + o[8]; j < e1; ++j)
        dsum += __int_as_float(edata[j].y);
    dinv[node] = rsqrtf(1.0f + dsum);            // +1 = self-loop weight
}

// --- node pass 1: h' = (X@W1) * dinv -------------------------------------
__global__ void node1_kernel(const float* __restrict__ X, const float* __restrict__ W1,
                             const float* __restrict__ dinv, float* __restrict__ h, int N) {
    __shared__ float w[48];
    if (threadIdx.x < 48) w[threadIdx.x] = W1[threadIdx.x];
    __syncthreads();
    int i = blockIdx.x * blockDim.x + threadIdx.x;
    if (i >= N) return;
    float x0 = X[3 * i], x1 = X[3 * i + 1], x2 = X[3 * i + 2];
    float di = dinv[i];
    float4* hp = (float4*)(h + (size_t)i * 16);
#pragma unroll
    for (int k = 0; k < 4; ++k) {
        float4 v;
        v.x = (x0 * w[4 * k + 0] + x1 * w[16 + 4 * k + 0] + x2 * w[32 + 4 * k + 0]) * di;
        v.y = (x0 * w[4 * k + 1] + x1 * w[16 + 4 * k + 1] + x2 * w[32 + 4 * k + 1]) * di;
        v.z = (x0 * w[4 * k + 2] + x1 * w[16 + 4 * k + 2] + x2 * w[32 + 4 * k + 2]) * di;
        v.w = (x0 * w[4 * k + 3] + x1 * w[16 + 4 * k + 3] + x2 * w[32 + 4 * k + 3]) * di;
        hp[k] = v;
    }
}

// --- agg pass 1, tile-phased gather, fused node2 -------------------------
// 512 threads = 128 node-groups x 4 lanes; 2 nodes per group (i, i+128).
// acc seeded with self h'; epilogue: x=leaky(di*acc+b1); h2'=(x@W2)*di.
__global__ __launch_bounds__(512) void
aggA_kernel(const int* __restrict__ row, const uint4* __restrict__ tcnt,
            const int2* __restrict__ edata, const float* __restrict__ dinv,
            const float* __restrict__ hprime, const float* __restrict__ b1,
            const float* __restrict__ W2, float* __restrict__ h2) {
    __shared__ float w[256];
    __shared__ float bb[16];
    __shared__ float sx[128][17];
    int t = threadIdx.x;
    if (t < 256) w[t] = W2[t];
    else if (t < 272) bb[t - 256] = b1[t - 256];
    int ln = t >> 2, l = t & 3;
    int iA = blockIdx.x * 256 + ln, iB = iA + 128;
    const float4* hp = (const float4*)hprime;
    int eA = row[iA], eB = row[iB];
    uint4 cAv = tcnt[iA], cBv = tcnt[iB];
    unsigned ca[4] = {cAv.x, cAv.y, cAv.z, cAv.w};
    unsigned cb[4] = {cBv.x, cBv.y, cBv.z, cBv.w};
    float diA = dinv[iA], diB = dinv[iB];
    float4 accA = hp[(size_t)iA * 4 + l];    // self-loop seed (h')
    float4 accB = hp[(size_t)iB * 4 + l];
#pragma unroll
    for (int tt = 0; tt < NTILE; ++tt) {
        int nA = (ca[tt >> 1] >> ((tt & 1) * 16)) & 0xFFFF;
        int nB = (cb[tt >> 1] >> ((tt & 1) * 16)) & 0xFFFF;
        for (int e = eA + nA; eA < e; ++eA) {
            int2 ed = edata[eA];
            float ewv = __int_as_float(ed.y);
            float4 v = hp[(size_t)ed.x * 4 + l];
            accA.x += v.x * ewv; accA.y += v.y * ewv;
            accA.z += v.z * ewv; accA.w += v.w * ewv;
        }
        for (int e = eB + nB; eB < e; ++eB) {
            int2 ed = edata[eB];
            float ewv = __int_as_float(ed.y);
            float4 v = hp[(size_t)ed.x * 4 + l];
            accB.x += v.x * ewv; accB.y += v.y * ewv;
            accB.z += v.z * ewv; accB.w += v.w * ewv;
        }
        __syncthreads();
    }
    // fused node2: x = leaky(di*acc + b1); h2' = (x@W2)*di (LDS transpose)
    sx[ln][4 * l + 0] = leaky(diA * accA.x + bb[4 * l + 0]);
    sx[ln][4 * l + 1] = leaky(diA * accA.y + bb[4 * l + 1]);
    sx[ln][4 * l + 2] = leaky(diA * accA.z + bb[4 * l + 2]);
    sx[ln][4 * l + 3] = leaky(diA * accA.w + bb[4 * l + 3]);
    __syncthreads();
    {
        float a0 = 0.f, a1 = 0.f, a2 = 0.f, a3 = 0.f;
#pragma unroll
        for (int q = 0; q < 16; ++q) {
            float xv = sx[ln][q];
            a0 += xv * w[q * 16 + 4 * l + 0];
            a1 += xv * w[q * 16 + 4 * l + 1];
            a2 += xv * w[q * 16 + 4 * l + 2];
            a3 += xv * w[q * 16 + 4 * l + 3];
        }
        ((float4*)h2)[(size_t)iA * 4 + l] = make_float4(a0 * diA, a1 * diA, a2 * diA, a3 * diA);
    }
    __syncthreads();
    sx[ln][4 * l + 0] = leaky(diB * accB.x + bb[4 * l + 0]);
    sx[ln][4 * l + 1] = leaky(diB * accB.y + bb[4 * l + 1]);
    sx[ln][4 * l + 2] = leaky(diB * accB.z + bb[4 * l + 2]);
    sx[ln][4 * l + 3] = leaky(diB * accB.w + bb[4 * l + 3]);
    __syncthreads();
    {
        float a0 = 0.f, a1 = 0.f, a2 = 0.f, a3 = 0.f;
#pragma unroll
        for (int q = 0; q < 16; ++q) {
            float xv = sx[ln][q];
            a0 += xv * w[q * 16 + 4 * l + 0];
            a1 += xv * w[q * 16 + 4 * l + 1];
            a2 += xv * w[q * 16 + 4 * l + 2];
            a3 += xv * w[q * 16 + 4 * l + 3];
        }
        ((float4*)h2)[(size_t)iB * 4 + l] = make_float4(a0 * diB, a1 * diB, a2 * diB, a3 * diB);
    }
}

// --- agg pass 2, tile-phased gather (pool applies b2+leaky) --------------
__global__ __launch_bounds__(512) void
aggB_kernel(const int* __restrict__ row, const uint4* __restrict__ tcnt,
            const int2* __restrict__ edata, const float* __restrict__ dinv,
            const float* __restrict__ h2prime, float* __restrict__ agg2) {
    int t = threadIdx.x;
    int ln = t >> 2, l = t & 3;
    int iA = blockIdx.x * 256 + ln, iB = iA + 128;
    const float4* hp = (const float4*)h2prime;
    int eA = row[iA], eB = row[iB];
    uint4 cAv = tcnt[iA], cBv = tcnt[iB];
    unsigned ca[4] = {cAv.x, cAv.y, cAv.z, cAv.w};
    unsigned cb[4] = {cBv.x, cBv.y, cBv.z, cBv.w};
    float diA = dinv[iA], diB = dinv[iB];
    float4 accA = hp[(size_t)iA * 4 + l];    // self-loop seed (h2')
    float4 accB = hp[(size_t)iB * 4 + l];
#pragma unroll
    for (int tt = 0; tt < NTILE; ++tt) {
        int nA = (ca[tt >> 1] >> ((tt & 1) * 16)) & 0xFFFF;
        int nB = (cb[tt >> 1] >> ((tt & 1) * 16)) & 0xFFFF;
        for (int e = eA + nA; eA < e; ++eA) {
            int2 ed = edata[eA];
            float ewv = __int_as_float(ed.y);
            float4 v = hp[(size_t)ed.x * 4 + l];
            accA.x += v.x * ewv; accA.y += v.y * ewv;
            accA.z += v.z * ewv; accA.w += v.w * ewv;
        }
        for (int e = eB + nB; eB < e; ++eB) {
            int2 ed = edata[eB];
            float ewv = __int_as_float(ed.y);
            float4 v = hp[(size_t)ed.x * 4 + l];
            accB.x += v.x * ewv; accB.y += v.y * ewv;
            accB.z += v.z * ewv; accB.w += v.w * ewv;
        }
        __syncthreads();
    }
    ((float4*)agg2)[(size_t)iA * 4 + l] =
        make_float4(accA.x * diA, accA.y * diA, accA.z * diA, accA.w * diA);
    ((float4*)agg2)[(size_t)iB * 4 + l] =
        make_float4(accB.x * diB, accB.y * diB, accB.z * diB, accB.w * diB);
}

// --- tiny MLP head: 16 ->16 ->16 ->2 -------------------------------------
__device__ void head_mlp(const float* pooled,
                         const float* __restrict__ Wa, const float* __restrict__ ba,
                         const float* __restrict__ Wb, const float* __restrict__ bb,
                         const float* __restrict__ Wc, const float* __restrict__ bc,
                         float* o) {
    float t[16], u[16];
#pragma unroll
    for (int f = 0; f < 16; ++f) {
        float a = ba[f];
        for (int k = 0; k < 16; ++k) a += pooled[k] * Wa[k * 16 + f];
        t[f] = leaky(a);
    }
#pragma unroll
    for (int f = 0; f < 16; ++f) {
        float a = bb[f];
        for (int k = 0; k < 16; ++k) a += t[k] * Wb[k * 16 + f];
        u[f] = leaky(a);
    }
    float o0 = bc[0], o1 = bc[1];
    for (int k = 0; k < 16; ++k) { o0 += u[k] * Wc[2 * k]; o1 += u[k] * Wc[2 * k + 1]; }
    o[0] = o0; o[1] = o1;
}

// --- pool (block per graph; Batching sorted -> binary search) + heads ----
__global__ void pool_head_kernel(const float* __restrict__ agg2, const float* __restrict__ b2,
                                 const int* __restrict__ batching, int N,
                                 const float* __restrict__ Wp1, const float* __restrict__ bp1,
                                 const float* __restrict__ Wp2, const float* __restrict__ bp2,
                                 const float* __restrict__ Wp3, const float* __restrict__ bp3,
                                 const float* __restrict__ Wt1, const float* __restrict__ bt1,
                                 const float* __restrict__ Wt2, const float* __restrict__ bt2,
                                 const float* __restrict__ Wt3, const float* __restrict__ bt3,
                                 float* __restrict__ out) {
    int g = blockIdx.x;
    __shared__ int bounds[2];
    if (threadIdx.x < 2) {
        int v = g + (int)threadIdx.x;
        int lo = 0, hi = N;
        while (lo < hi) { int m = (lo + hi) >> 1; if (batching[m] < v) lo = m + 1; else hi = m; }
        bounds[threadIdx.x] = lo;
    }
    __syncthreads();
    int lo = bounds[0], hi = bounds[1];
    int f = threadIdx.x & 15, r = threadIdx.x >> 4;    // 16 rows x 16 features
    float bf = b2[f];
    float acc = 0.f;
    for (int i = lo + r; i < hi; i += 16) acc += leaky(agg2[(size_t)i * 16 + f] + bf);
    __shared__ float red[16][17];
    red[r][f] = acc;
    __syncthreads();
    __shared__ float pooled[16];
    if (r == 0) {
        float s = 0.f;
#pragma unroll
        for (int k = 0; k < 16; ++k) s += red[k][f];
        pooled[f] = s / fmaxf((float)(hi - lo), 1.0f);
    }
    __syncthreads();
    if (threadIdx.x == 0) {
        float o[2];
        head_mlp(pooled, Wp1, bp1, Wp2, bp2, Wp3, bp3, o);
        out[4 * g + 0] = o[0]; out[4 * g + 1] = o[1];
    } else if (threadIdx.x == 1) {
        float o[2];
        head_mlp(pooled, Wt1, bt1, Wt2, bt2, Wt3, bt3, o);
        out[4 * g + 2] = o[0]; out[4 * g + 3] = o[1];
    }
}

extern "C" void kernel_launch(void* const* d_in, const int* in_sizes, int n_in,
                              void* d_out, int out_size, void* d_ws, size_t ws_size,
                              hipStream_t stream) {
    const float* X        = (const float*)d_in[0];
    const int*   ei       = (const int*)d_in[1];
    const float* ew       = (const float*)d_in[2];
    const int*   batching = (const int*)d_in[3];
    const float* W1  = (const float*)d_in[5];  const float* b1  = (const float*)d_in[6];
    const float* W2  = (const float*)d_in[7];  const float* b2  = (const float*)d_in[8];
    const float* Wp1 = (const float*)d_in[9];  const float* bp1 = (const float*)d_in[10];
    const float* Wp2 = (const float*)d_in[11]; const float* bp2 = (const float*)d_in[12];
    const float* Wp3 = (const float*)d_in[13]; const float* bp3 = (const float*)d_in[14];
    const float* Wt1 = (const float*)d_in[15]; const float* bt1 = (const float*)d_in[16];
    const float* Wt2 = (const float*)d_in[17]; const float* bt2 = (const float*)d_in[18];
    const float* Wt3 = (const float*)d_in[19]; const float* bt3 = (const float*)d_in[20];

    const int N = in_sizes[3];        // 262144 = 512 * 512
    const int E = in_sizes[2];        // 4194304
    const int G = out_size / 4;       // 1024
    const int* src = ei;
    const int* dst = ei + E;

    char* ws = (char*)d_ws;
    size_t off = 0;
    int2*  edata = (int2*)(ws + off);  off += (size_t)E * 8;              // 32 MB fine CSR
    char*  regionA = ws + off;         off += (size_t)N * 64 * 3;         // 48 MB
    // regionA phase 1: coarse buckets (40 MB); phase 2: h' | h2' | agg2
    int2*  coarse = (int2*)regionA;
    float* hprime = (float*)regionA;
    float* h2     = (float*)(regionA + (size_t)N * 64);
    float* agg2   = (float*)(regionA + (size_t)N * 128);
    int*   bucketCursor = (int*)(ws + off); off += NBUCK * 4;
    int*   bucketBase   = (int*)(ws + off); off += NBUCK * 4;
    int*   row   = (int*)(ws + off);   off += (size_t)(N + 4) * 4;
    float* dinv  = (float*)(ws + off); off += (size_t)N * 4;
    uint4* tcnt  = (uint4*)(ws + off); off += (size_t)N * 16;             // 4 MB
    float* out   = (float*)d_out;

    hipMemsetAsync(bucketCursor, 0, NBUCK * 4, stream);

    const int tb = 256;
    binA_kernel<<<(E + CHUNK - 1) / CHUNK, tb, 0, stream>>>(src, dst, ew, bucketCursor, coarse, E);
    bscan_kernel<<<1, NBUCK, 0, stream>>>(bucketCursor, bucketBase, row, N, E);
    binB_kernel<<<NBUCK, 512, 0, stream>>>(bucketCursor, bucketBase, coarse, edata, row, dinv, tcnt);
    node1_kernel<<<(N + tb - 1) / tb, tb, 0, stream>>>(X, W1, dinv, hprime, N);
    aggA_kernel<<<N / 256, 512, 0, stream>>>(row, tcnt, edata, dinv, hprime, b1, W2, h2);
    aggB_kernel<<<N / 256, 512, 0, stream>>>(row, tcnt, edata, dinv, h2, agg2);
    pool_head_kernel<<<G, tb, 0, stream>>>(agg2, b2, batching, N,
                                           Wp1, bp1, Wp2, bp2, Wp3, bp3,
                                           Wt1, bt1, Wt2, bt2, Wt3, bt3, out);
}

// Round 4
// 374.854 us; speedup vs baseline: 2.6229x; 1.1461x over previous
//
#include <hip/hip_runtime.h>

// GCN: 2x GCNConv(sym-norm, self-loops) + mean-pool + 2 MLP heads.
// R6: binB sorts entirely in LDS and writes edata coalesced.
// R3 lesson: scattered 8B global stores across 64KB windows x 64 live
// buckets/XCD overflow L2 -> partial-line eviction churn (WRITE 208MB vs
// 38MB ideal). Staging the permutation in LDS (80KB) and streaming out
// coalesced removes the churn, the 2nd coarse read, and the edata re-read.
//  - agg: gather-based tile-phased (proven), h' pre-scaled by dinv.
//  - no float LDS atomics anywhere (R2 lesson: CAS retry storm).

#define NBUCK 512          // coarse buckets = dst >> 9
#define BCAP  10240        // slack capacity per bucket (mean 8192, sigma ~90)
#define CHUNK 4096         // edges per pass-A block
#define NTILE 8            // src tiles = src >> 15 (2MB of h' per tile)
#define TSH   15
#define RCAP  20           // BCAP/512 register-staged edges per thread

__device__ __forceinline__ float leaky(float x) { return x > 0.f ? x : 0.01f * x; }

// --- Pass A: bin edges by dst>>9 into slack-capacity coarse buckets ------
__global__ __launch_bounds__(256) void
binA_kernel(const int* __restrict__ src, const int* __restrict__ dst,
            const float* __restrict__ ew, int* __restrict__ bucketCursor,
            int2* __restrict__ coarse, int E) {
    __shared__ int lhist[NBUCK], lbase[NBUCK], lcur[NBUCK], gbase[NBUCK];
    __shared__ int tmp[256];
    __shared__ int2 stag[CHUNK];
    __shared__ unsigned short sbuck[CHUNK];
    int t = threadIdx.x;
    int base = blockIdx.x * CHUNK;
    for (int b = t; b < NBUCK; b += 256) { lhist[b] = 0; lcur[b] = 0; }
    __syncthreads();
    int n = min(CHUNK, E - base);
    int myDst[16], mySrc[16]; float myEw[16];
#pragma unroll
    for (int k = 0; k < 16; ++k) {
        int j = t + k * 256;                       // coalesced
        if (j < n) {
            int d = dst[base + j];
            myDst[k] = d; mySrc[k] = src[base + j]; myEw[k] = ew[base + j];
            atomicAdd(&lhist[d >> 9], 1);
        } else myDst[k] = -1;
    }
    __syncthreads();
    // exclusive scan of lhist (512 entries, 256 threads, pair trick)
    tmp[t] = lhist[2 * t] + lhist[2 * t + 1];
    __syncthreads();
    for (int off = 1; off < 256; off <<= 1) {
        int v = (t >= off) ? tmp[t - off] : 0;
        __syncthreads();
        tmp[t] += v;
        __syncthreads();
    }
    int pb = (t == 0) ? 0 : tmp[t - 1];
    lbase[2 * t] = pb;
    lbase[2 * t + 1] = pb + lhist[2 * t];
    __syncthreads();
    // reserve global space per bucket (one atomic per non-empty bucket)
    for (int b = t; b < NBUCK; b += 256) {
        int c = lhist[b];
        gbase[b] = c ? atomicAdd(&bucketCursor[b], c) : 0;
    }
    // stage into LDS, sorted by bucket; pack (src | ldst<<18, ew)
    for (int k = 0; k < 16; ++k) {
        int d = myDst[k];
        if (d >= 0) {
            int b = d >> 9;
            int p = lbase[b] + atomicAdd(&lcur[b], 1);
            stag[p] = make_int2(mySrc[k] | ((d & 511) << 18), __float_as_int(myEw[k]));
            sbuck[p] = (unsigned short)b;
        }
    }
    __syncthreads();
    // write out: consecutive j -> consecutive addresses within bucket runs
    for (int j = t; j < n; j += 256) {
        int b = sbuck[j];
        coarse[(size_t)b * BCAP + gbase[b] + (j - lbase[b])] = stag[j];
    }
}

// --- scan bucket counts -> bucket bases (1 block x 512) ------------------
__global__ void bscan_kernel(const int* __restrict__ bucketCursor,
                             int* __restrict__ bucketBase, int* __restrict__ row,
                             int N, int E) {
    __shared__ int s[NBUCK];
    int t = threadIdx.x;
    int v = bucketCursor[t];
    s[t] = v;
    __syncthreads();
    for (int off = 1; off < NBUCK; off <<= 1) {
        int x = (t >= off) ? s[t - off] : 0;
        __syncthreads();
        s[t] += x;
        __syncthreads();
    }
    bucketBase[t] = s[t] - v;
    if (t == 0) row[N] = E;
}

// --- Pass B: LDS-staged (ld,tile) counting sort; coalesced writeout ------
// Single global read of coarse into registers; sort permutation resolved
// entirely in LDS (80KB staging); edata written as a coalesced stream;
// deg summed from LDS. Int atomics only.
__global__ __launch_bounds__(512, 2) void
binB_kernel(const int* __restrict__ bucketCursor, const int* __restrict__ bucketBase,
            const int2* __restrict__ coarse, int2* __restrict__ edata,
            int* __restrict__ row, float* __restrict__ dinv,
            uint4* __restrict__ tcnt) {
    __shared__ int2 sedata[BCAP];         // 80 KB sort staging
    __shared__ int loff[NBUCK * NTILE];   // counts -> offsets -> cursors
    __shared__ int tmp[512];
    int b = blockIdx.x, t = threadIdx.x;
    for (int i = t; i < NBUCK * NTILE; i += 512) loff[i] = 0;
    __syncthreads();
    int cnt = bucketCursor[b];
    int gb  = bucketBase[b];
    const int2* cb = coarse + (size_t)b * BCAP;
    int2 myE[RCAP]; int myKey[RCAP];
#pragma unroll
    for (int k = 0; k < RCAP; ++k) {
        int j = t + k * 512;               // coalesced
        if (j < cnt) {
            int2 e = cb[j];
            myE[k] = e;
            myKey[k] = (((e.x >> 18) & 511) << 3) | ((e.x & 0x3FFFF) >> TSH);
            atomicAdd(&loff[myKey[k]], 1);
        } else myKey[k] = -1;
    }
    __syncthreads();
    // exclusive scan over 4096 (thread t owns node t's 8 tile-bins)
    int base8 = t * 8, s = 0;
#pragma unroll
    for (int k = 0; k < 8; ++k) s += loff[base8 + k];
    tmp[t] = s;
    __syncthreads();
    for (int off = 1; off < 512; off <<= 1) {
        int v = (t >= off) ? tmp[t - off] : 0;
        __syncthreads();
        tmp[t] += v;
        __syncthreads();
    }
    int run = tmp[t] - s;
    int o[9];
#pragma unroll
    for (int k = 0; k < 8; ++k) { int v = loff[base8 + k]; o[k] = run; loff[base8 + k] = run; run += v; }
    o[8] = run;                            // end of node t's edge range
    __syncthreads();
    int node = b * 512 + t;
    row[node] = gb + o[0];
    uint4 p;
    p.x = (unsigned)(o[1] - o[0]) | ((unsigned)(o[2] - o[1]) << 16);
    p.y = (unsigned)(o[3] - o[2]) | ((unsigned)(o[4] - o[3]) << 16);
    p.z = (unsigned)(o[5] - o[4]) | ((unsigned)(o[6] - o[5]) << 16);
    p.w = (unsigned)(o[7] - o[6]) | ((unsigned)(o[8] - o[7]) << 16);
    tcnt[node] = p;
    // place into LDS staging (loff is the moving cursor)
#pragma unroll
    for (int k = 0; k < RCAP; ++k) {
        if (myKey[k] >= 0) {
            int pos = atomicAdd(&loff[myKey[k]], 1);
            sedata[pos] = make_int2(myE[k].x & 0x3FFFF, myE[k].y);
        }
    }
    __syncthreads();
    // coalesced streaming writeout
    for (int j = t; j < cnt; j += 512) edata[gb + j] = sedata[j];
    // deg = sum of ew over this node's LDS-resident run
    float dsum = 0.f;
    for (int j = o[0]; j < o[8]; ++j) dsum += __int_as_float(sedata[j].y);
    dinv[node] = rsqrtf(1.0f + dsum);      // +1 = self-loop weight
}

// --- node pass 1: h' = (X@W1) * dinv -------------------------------------
__global__ void node1_kernel(const float* __restrict__ X, const float* __restrict__ W1,
                             const float* __restrict__ dinv, float* __restrict__ h, int N) {
    __shared__ float w[48];
    if (threadIdx.x < 48) w[threadIdx.x] = W1[threadIdx.x];
    __syncthreads();
    int i = blockIdx.x * blockDim.x + threadIdx.x;
    if (i >= N) return;
    float x0 = X[3 * i], x1 = X[3 * i + 1], x2 = X[3 * i + 2];
    float di = dinv[i];
    float4* hp = (float4*)(h + (size_t)i * 16);
#pragma unroll
    for (int k = 0; k < 4; ++k) {
        float4 v;
        v.x = (x0 * w[4 * k + 0] + x1 * w[16 + 4 * k + 0] + x2 * w[32 + 4 * k + 0]) * di;
        v.y = (x0 * w[4 * k + 1] + x1 * w[16 + 4 * k + 1] + x2 * w[32 + 4 * k + 1]) * di;
        v.z = (x0 * w[4 * k + 2] + x1 * w[16 + 4 * k + 2] + x2 * w[32 + 4 * k + 2]) * di;
        v.w = (x0 * w[4 * k + 3] + x1 * w[16 + 4 * k + 3] + x2 * w[32 + 4 * k + 3]) * di;
        hp[k] = v;
    }
}

// --- agg pass 1, tile-phased gather, fused node2 -------------------------
// 512 threads = 128 node-groups x 4 lanes; 2 nodes per group (i, i+128).
// acc seeded with self h'; epilogue: x=leaky(di*acc+b1); h2'=(x@W2)*di.
__global__ __launch_bounds__(512) void
aggA_kernel(const int* __restrict__ row, const uint4* __restrict__ tcnt,
            const int2* __restrict__ edata, const float* __restrict__ dinv,
            const float* __restrict__ hprime, const float* __restrict__ b1,
            const float* __restrict__ W2, float* __restrict__ h2) {
    __shared__ float w[256];
    __shared__ float bb[16];
    __shared__ float sx[128][17];
    int t = threadIdx.x;
    if (t < 256) w[t] = W2[t];
    else if (t < 272) bb[t - 256] = b1[t - 256];
    int ln = t >> 2, l = t & 3;
    int iA = blockIdx.x * 256 + ln, iB = iA + 128;
    const float4* hp = (const float4*)hprime;
    int eA = row[iA], eB = row[iB];
    uint4 cAv = tcnt[iA], cBv = tcnt[iB];
    unsigned ca[4] = {cAv.x, cAv.y, cAv.z, cAv.w};
    unsigned cb[4] = {cBv.x, cBv.y, cBv.z, cBv.w};
    float diA = dinv[iA], diB = dinv[iB];
    float4 accA = hp[(size_t)iA * 4 + l];    // self-loop seed (h')
    float4 accB = hp[(size_t)iB * 4 + l];
#pragma unroll
    for (int tt = 0; tt < NTILE; ++tt) {
        int nA = (ca[tt >> 1] >> ((tt & 1) * 16)) & 0xFFFF;
        int nB = (cb[tt >> 1] >> ((tt & 1) * 16)) & 0xFFFF;
        for (int e = eA + nA; eA < e; ++eA) {
            int2 ed = edata[eA];
            float ewv = __int_as_float(ed.y);
            float4 v = hp[(size_t)ed.x * 4 + l];
            accA.x += v.x * ewv; accA.y += v.y * ewv;
            accA.z += v.z * ewv; accA.w += v.w * ewv;
        }
        for (int e = eB + nB; eB < e; ++eB) {
            int2 ed = edata[eB];
            float ewv = __int_as_float(ed.y);
            float4 v = hp[(size_t)ed.x * 4 + l];
            accB.x += v.x * ewv; accB.y += v.y * ewv;
            accB.z += v.z * ewv; accB.w += v.w * ewv;
        }
        __syncthreads();
    }
    // fused node2: x = leaky(di*acc + b1); h2' = (x@W2)*di (LDS transpose)
    sx[ln][4 * l + 0] = leaky(diA * accA.x + bb[4 * l + 0]);
    sx[ln][4 * l + 1] = leaky(diA * accA.y + bb[4 * l + 1]);
    sx[ln][4 * l + 2] = leaky(diA * accA.z + bb[4 * l + 2]);
    sx[ln][4 * l + 3] = leaky(diA * accA.w + bb[4 * l + 3]);
    __syncthreads();
    {
        float a0 = 0.f, a1 = 0.f, a2 = 0.f, a3 = 0.f;
#pragma unroll
        for (int q = 0; q < 16; ++q) {
            float xv = sx[ln][q];
            a0 += xv * w[q * 16 + 4 * l + 0];
            a1 += xv * w[q * 16 + 4 * l + 1];
            a2 += xv * w[q * 16 + 4 * l + 2];
            a3 += xv * w[q * 16 + 4 * l + 3];
        }
        ((float4*)h2)[(size_t)iA * 4 + l] = make_float4(a0 * diA, a1 * diA, a2 * diA, a3 * diA);
    }
    __syncthreads();
    sx[ln][4 * l + 0] = leaky(diB * accB.x + bb[4 * l + 0]);
    sx[ln][4 * l + 1] = leaky(diB * accB.y + bb[4 * l + 1]);
    sx[ln][4 * l + 2] = leaky(diB * accB.z + bb[4 * l + 2]);
    sx[ln][4 * l + 3] = leaky(diB * accB.w + bb[4 * l + 3]);
    __syncthreads();
    {
        float a0 = 0.f, a1 = 0.f, a2 = 0.f, a3 = 0.f;
#pragma unroll
        for (int q = 0; q < 16; ++q) {
            float xv = sx[ln][q];
            a0 += xv * w[q * 16 + 4 * l + 0];
            a1 += xv * w[q * 16 + 4 * l + 1];
            a2 += xv * w[q * 16 + 4 * l + 2];
            a3 += xv * w[q * 16 + 4 * l + 3];
        }
        ((float4*)h2)[(size_t)iB * 4 + l] = make_float4(a0 * diB, a1 * diB, a2 * diB, a3 * diB);
    }
}

// --- agg pass 2, tile-phased gather (pool applies b2+leaky) --------------
__global__ __launch_bounds__(512) void
aggB_kernel(const int* __restrict__ row, const uint4* __restrict__ tcnt,
            const int2* __restrict__ edata, const float* __restrict__ dinv,
            const float* __restrict__ h2prime, float* __restrict__ agg2) {
    int t = threadIdx.x;
    int ln = t >> 2, l = t & 3;
    int iA = blockIdx.x * 256 + ln, iB = iA + 128;
    const float4* hp = (const float4*)h2prime;
    int eA = row[iA], eB = row[iB];
    uint4 cAv = tcnt[iA], cBv = tcnt[iB];
    unsigned ca[4] = {cAv.x, cAv.y, cAv.z, cAv.w};
    unsigned cb[4] = {cBv.x, cBv.y, cBv.z, cBv.w};
    float diA = dinv[iA], diB = dinv[iB];
    float4 accA = hp[(size_t)iA * 4 + l];    // self-loop seed (h2')
    float4 accB = hp[(size_t)iB * 4 + l];
#pragma unroll
    for (int tt = 0; tt < NTILE; ++tt) {
        int nA = (ca[tt >> 1] >> ((tt & 1) * 16)) & 0xFFFF;
        int nB = (cb[tt >> 1] >> ((tt & 1) * 16)) & 0xFFFF;
        for (int e = eA + nA; eA < e; ++eA) {
            int2 ed = edata[eA];
            float ewv = __int_as_float(ed.y);
            float4 v = hp[(size_t)ed.x * 4 + l];
            accA.x += v.x * ewv; accA.y += v.y * ewv;
            accA.z += v.z * ewv; accA.w += v.w * ewv;
        }
        for (int e = eB + nB; eB < e; ++eB) {
            int2 ed = edata[eB];
            float ewv = __int_as_float(ed.y);
            float4 v = hp[(size_t)ed.x * 4 + l];
            accB.x += v.x * ewv; accB.y += v.y * ewv;
            accB.z += v.z * ewv; accB.w += v.w * ewv;
        }
        __syncthreads();
    }
    ((float4*)agg2)[(size_t)iA * 4 + l] =
        make_float4(accA.x * diA, accA.y * diA, accA.z * diA, accA.w * diA);
    ((float4*)agg2)[(size_t)iB * 4 + l] =
        make_float4(accB.x * diB, accB.y * diB, accB.z * diB, accB.w * diB);
}

// --- tiny MLP head: 16 ->16 ->16 ->2 -------------------------------------
__device__ void head_mlp(const float* pooled,
                         const float* __restrict__ Wa, const float* __restrict__ ba,
                         const float* __restrict__ Wb, const float* __restrict__ bb,
                         const float* __restrict__ Wc, const float* __restrict__ bc,
                         float* o) {
    float t[16], u[16];
#pragma unroll
    for (int f = 0; f < 16; ++f) {
        float a = ba[f];
        for (int k = 0; k < 16; ++k) a += pooled[k] * Wa[k * 16 + f];
        t[f] = leaky(a);
    }
#pragma unroll
    for (int f = 0; f < 16; ++f) {
        float a = bb[f];
        for (int k = 0; k < 16; ++k) a += t[k] * Wb[k * 16 + f];
        u[f] = leaky(a);
    }
    float o0 = bc[0], o1 = bc[1];
    for (int k = 0; k < 16; ++k) { o0 += u[k] * Wc[2 * k]; o1 += u[k] * Wc[2 * k + 1]; }
    o[0] = o0; o[1] = o1;
}

// --- pool (block per graph; Batching sorted -> binary search) + heads ----
__global__ void pool_head_kernel(const float* __restrict__ agg2, const float* __restrict__ b2,
                                 const int* __restrict__ batching, int N,
                                 const float* __restrict__ Wp1, const float* __restrict__ bp1,
                                 const float* __restrict__ Wp2, const float* __restrict__ bp2,
                                 const float* __restrict__ Wp3, const float* __restrict__ bp3,
                                 const float* __restrict__ Wt1, const float* __restrict__ bt1,
                                 const float* __restrict__ Wt2, const float* __restrict__ bt2,
                                 const float* __restrict__ Wt3, const float* __restrict__ bt3,
                                 float* __restrict__ out) {
    int g = blockIdx.x;
    __shared__ int bounds[2];
    if (threadIdx.x < 2) {
        int v = g + (int)threadIdx.x;
        int lo = 0, hi = N;
        while (lo < hi) { int m = (lo + hi) >> 1; if (batching[m] < v) lo = m + 1; else hi = m; }
        bounds[threadIdx.x] = lo;
    }
    __syncthreads();
    int lo = bounds[0], hi = bounds[1];
    int f = threadIdx.x & 15, r = threadIdx.x >> 4;    // 16 rows x 16 features
    float bf = b2[f];
    float acc = 0.f;
    for (int i = lo + r; i < hi; i += 16) acc += leaky(agg2[(size_t)i * 16 + f] + bf);
    __shared__ float red[16][17];
    red[r][f] = acc;
    __syncthreads();
    __shared__ float pooled[16];
    if (r == 0) {
        float s = 0.f;
#pragma unroll
        for (int k = 0; k < 16; ++k) s += red[k][f];
        pooled[f] = s / fmaxf((float)(hi - lo), 1.0f);
    }
    __syncthreads();
    if (threadIdx.x == 0) {
        float o[2];
        head_mlp(pooled, Wp1, bp1, Wp2, bp2, Wp3, bp3, o);
        out[4 * g + 0] = o[0]; out[4 * g + 1] = o[1];
    } else if (threadIdx.x == 1) {
        float o[2];
        head_mlp(pooled, Wt1, bt1, Wt2, bt2, Wt3, bt3, o);
        out[4 * g + 2] = o[0]; out[4 * g + 3] = o[1];
    }
}

extern "C" void kernel_launch(void* const* d_in, const int* in_sizes, int n_in,
                              void* d_out, int out_size, void* d_ws, size_t ws_size,
                              hipStream_t stream) {
    const float* X        = (const float*)d_in[0];
    const int*   ei       = (const int*)d_in[1];
    const float* ew       = (const float*)d_in[2];
    const int*   batching = (const int*)d_in[3];
    const float* W1  = (const float*)d_in[5];  const float* b1  = (const float*)d_in[6];
    const float* W2  = (const float*)d_in[7];  const float* b2  = (const float*)d_in[8];
    const float* Wp1 = (const float*)d_in[9];  const float* bp1 = (const float*)d_in[10];
    const float* Wp2 = (const float*)d_in[11]; const float* bp2 = (const float*)d_in[12];
    const float* Wp3 = (const float*)d_in[13]; const float* bp3 = (const float*)d_in[14];
    const float* Wt1 = (const float*)d_in[15]; const float* bt1 = (const float*)d_in[16];
    const float* Wt2 = (const float*)d_in[17]; const float* bt2 = (const float*)d_in[18];
    const float* Wt3 = (const float*)d_in[19]; const float* bt3 = (const float*)d_in[20];

    const int N = in_sizes[3];        // 262144 = 512 * 512
    const int E = in_sizes[2];        // 4194304
    const int G = out_size / 4;       // 1024
    const int* src = ei;
    const int* dst = ei + E;

    char* ws = (char*)d_ws;
    size_t off = 0;
    int2*  edata = (int2*)(ws + off);  off += (size_t)E * 8;              // 32 MB fine CSR
    char*  regionA = ws + off;         off += (size_t)N * 64 * 3;         // 48 MB
    // regionA phase 1: coarse buckets (40 MB); phase 2: h' | h2' | agg2
    int2*  coarse = (int2*)regionA;
    float* hprime = (float*)regionA;
    float* h2     = (float*)(regionA + (size_t)N * 64);
    float* agg2   = (float*)(regionA + (size_t)N * 128);
    int*   bucketCursor = (int*)(ws + off); off += NBUCK * 4;
    int*   bucketBase   = (int*)(ws + off); off += NBUCK * 4;
    int*   row   = (int*)(ws + off);   off += (size_t)(N + 4) * 4;
    float* dinv  = (float*)(ws + off); off += (size_t)N * 4;
    uint4* tcnt  = (uint4*)(ws + off); off += (size_t)N * 16;             // 4 MB
    float* out   = (float*)d_out;

    hipMemsetAsync(bucketCursor, 0, NBUCK * 4, stream);

    const int tb = 256;
    binA_kernel<<<(E + CHUNK - 1) / CHUNK, tb, 0, stream>>>(src, dst, ew, bucketCursor, coarse, E);
    bscan_kernel<<<1, NBUCK, 0, stream>>>(bucketCursor, bucketBase, row, N, E);
    binB_kernel<<<NBUCK, 512, 0, stream>>>(bucketCursor, bucketBase, coarse, edata, row, dinv, tcnt);
    node1_kernel<<<(N + tb - 1) / tb, tb, 0, stream>>>(X, W1, dinv, hprime, N);
    aggA_kernel<<<N / 256, 512, 0, stream>>>(row, tcnt, edata, dinv, hprime, b1, W2, h2);
    aggB_kernel<<<N / 256, 512, 0, stream>>>(row, tcnt, edata, dinv, h2, agg2);
    pool_head_kernel<<<G, tb, 0, stream>>>(agg2, b2, batching, N,
                                           Wp1, bp1, Wp2, bp2, Wp3, bp3,
                                           Wt1, bt1, Wt2, bt2, Wt3, bt3, out);
}